// Round 14
// baseline (5560.409 us; speedup 1.0000x reference)
//
#include <hip/hip_runtime.h>

#define T_ 25
#define V_ 10000

typedef short bf16x8 __attribute__((ext_vector_type(8)));
typedef float f32x4 __attribute__((ext_vector_type(4)));

__device__ __forceinline__ short f2bf(float x) {
  union { float f; unsigned u; } v; v.f = x;
  unsigned r = (v.u + 0x7fffu + ((v.u >> 16) & 1u)) >> 16;
  return (short)r;
}
__device__ __forceinline__ float sigm(float z) { return 1.f / (1.f + __expf(-z)); }
__device__ __forceinline__ float tanhfast(float z) {
  float e = __expf(2.f * z);
  return 1.f - 2.f / (e + 1.f);
}

__device__ __forceinline__ void gload_lds16(const void* g, void* l) {
  __builtin_amdgcn_global_load_lds((const __attribute__((address_space(1))) void*)g,
                                   (__attribute__((address_space(3))) void*)l, 16, 0, 0);
}

__device__ __forceinline__ void vwait0() { asm volatile("s_waitcnt vmcnt(0)" ::: "memory"); }
__device__ __forceinline__ void vwait_n(int n) {   // n folds to constant after unroll
  switch (n) {
    case 0:  asm volatile("s_waitcnt vmcnt(0)"  ::: "memory"); break;
    case 8:  asm volatile("s_waitcnt vmcnt(8)"  ::: "memory"); break;
    case 16: asm volatile("s_waitcnt vmcnt(16)" ::: "memory"); break;
    default: asm volatile("s_waitcnt vmcnt(0)"  ::: "memory"); break;
  }
}
__device__ __forceinline__ void ncload16(bf16x8* d, const short* p) {
  asm volatile("global_load_dwordx4 %0, %1, off" : "=v"(*d) : "v"(p) : "memory");
}
// coherent write-through stores (land at IC; no dirty per-XCD L2 lines)
__device__ __forceinline__ void cstores(short* p, int v) {
  asm volatile("global_store_short %0, %1, off sc0 sc1" :: "v"(p), "v"(v) : "memory");
}

// XOR-swizzled element offset inside a [16][512] bf16 A-buffer (granule = 8 shorts).
// Same involution on write (scalar/global) and read (b128) -> bank-conflict-free A reads.
__device__ __forceinline__ int swz(int row, int col) {
  return (row << 9) + ((((col >> 3) ^ (row & 7)) << 3) | (col & 7));
}

// -------- p2p flags: producer done-words, no RMW --------
__device__ __forceinline__ void setflag(int* bar, int role, int wg, int val) {
  vwait0();                        // drain this wave's global stores
  __syncthreads();                 // all waves done (also fences LDS for next phase)
  if (threadIdx.x == 0) {
    int* wp = bar + role * 256 + wg;
    asm volatile("global_store_dword %0, %1, off sc0 sc1" :: "v"(wp), "v"(val) : "memory");
  }
}
__device__ __forceinline__ void waitwords(const int* base, int cnt, int need) {
  if (threadIdx.x < 64) {
    int idx = (int)threadIdx.x < cnt ? (int)threadIdx.x : cnt - 1;
    const int* wp = base + idx;
    for (;;) {
      int v;
      asm volatile("global_load_dword %0, %1, off sc0 sc1" : "=v"(v) : "v"(wp) : "memory");
      asm volatile("s_waitcnt vmcnt(0)" ::: "memory");
      if (__all(v >= need)) break;
      __builtin_amdgcn_s_sleep(1);
    }
  }
  __syncthreads();
}

// ---------------- merged transpose + cast f32[R,C] -> bf16[C,R] ----------------
struct TJob { const float* src; short* dst; int R, C, t0; };
struct TJobs { TJob j[10]; };

__global__ void tcast_all(TJobs J) {
  __shared__ float t[32][33];
  int bid = blockIdx.x;
  int ji = 0;
  while (ji < 9 && bid >= J.j[ji + 1].t0) ji++;
  const float* src = J.j[ji].src;
  short* dst = J.j[ji].dst;
  int R = J.j[ji].R, C = J.j[ji].C;
  int rel = bid - J.j[ji].t0;
  int ctiles = (C + 31) >> 5;
  int rt0 = (rel / ctiles) * 32, ct0 = (rel % ctiles) * 32;
  int tx = threadIdx.x, ty = threadIdx.y; // 32x8
#pragma unroll
  for (int i = 0; i < 4; i++) {
    int r = rt0 + ty + i * 8, c = ct0 + tx;
    if (r < R && c < C) t[ty + i * 8][tx] = src[(size_t)r * C + c];
  }
  __syncthreads();
#pragma unroll
  for (int i = 0; i < 4; i++) {
    int c = ct0 + ty + i * 8, r = rt0 + tx;
    if (r < R && c < C) dst[(size_t)c * R + r] = f2bf(t[tx][ty + i * 8]);
  }
}

// ---------------- build X0 [T*B, 1024] bf16 : [emb(tok) | cnn] ----------------
__global__ void build_x0(const int* __restrict__ tok, const float* __restrict__ emb,
                         const float* __restrict__ cnn, short* __restrict__ X0) {
  int row = blockIdx.x;           // t*128 + b
  int t = row >> 7, b = row & 127;
  int tk = tok[b * T_ + t];
  const float* er = emb + (size_t)tk * 512;
  short* dst = X0 + (size_t)row * 1024;
  for (int i = threadIdx.x; i < 1024; i += 256)
    dst[i] = f2bf(i < 512 ? er[i] : cnn[b * 512 + (i - 512)]);
}

// ---------------- big MFMA GEMM core (A0 precompute + logits tiles) ----------------
struct GP {
  const short* A; const short* Bt;
  int lda, ldb, N, K;
  const float* bias0; const float* bias1; const float* bias2;
  float* fdst;
  float* outp; const float* bout;
};

template<int BM, int BN, int VAR>
__device__ __forceinline__ void gemm_core(const GP& p, short* la, short* lb, int bm, int bn, short* smem) {
  const int tid = threadIdx.x;
  const int wave = tid >> 6, lane = tid & 63;
  const int wm = wave >> 1, wn = wave & 1;
  constexpr int WM = BM / 2, WN = BN / 2;
  constexpr int MF = WM / 16, NF = WN / 16;
  const int lr = lane & 15, lg = lane >> 4;
  const short* Abase = p.A + (size_t)bm * BM * p.lda;
  const short* Bbase = p.Bt + (size_t)bn * BN * p.ldb;
  const int bnmax = p.N - bn * BN;
  f32x4 acc[MF][NF] = {};
  const int nkb = p.K >> 6;

  auto stA = [&](int buf, int k0) {
    constexpr int NI = BM / 32;
#pragma unroll
    for (int j = 0; j < NI; j++) {
      int glin = j * 256 + tid;
      int row = glin >> 3, gc = glin & 7;
      int gcs = gc ^ (row & 7);
      gload_lds16(Abase + (size_t)row * p.lda + k0 + gcs * 8,
                  &la[buf * BM * 64 + j * 2048 + wave * 512]);
    }
  };
  auto stB = [&](int buf, int k0) {
    constexpr int NI = BN / 32;
#pragma unroll
    for (int j = 0; j < NI; j++) {
      int glin = j * 256 + tid;
      int row = glin >> 3, gc = glin & 7;
      int gcs = gc ^ (row & 7);
      int rc = row < bnmax ? row : bnmax - 1;
      gload_lds16(Bbase + (size_t)rc * p.ldb + k0 + gcs * 8,
                  &lb[buf * BN * 64 + j * 2048 + wave * 512]);
    }
  };

  stA(0, 0); stB(0, 0);
  __syncthreads();
  int buf = 0;
  for (int kb = 0; kb < nkb; kb++) {
    if (kb + 1 < nkb) { stA(buf ^ 1, (kb + 1) * 64); stB(buf ^ 1, (kb + 1) * 64); }
    bf16x8 af[2][MF], bfr[2][NF];
#pragma unroll
    for (int ks = 0; ks < 2; ks++) {
#pragma unroll
      for (int m = 0; m < MF; m++) {
        int ar = wm * WM + m * 16 + lr;
        af[ks][m] = *(const bf16x8*)&la[buf * BM * 64 + (ar * 8 + ((ks * 4 + lg) ^ (ar & 7))) * 8];
      }
#pragma unroll
      for (int n = 0; n < NF; n++) {
        int br = wn * WN + n * 16 + lr;
        bfr[ks][n] = *(const bf16x8*)&lb[buf * BN * 64 + (br * 8 + ((ks * 4 + lg) ^ (br & 7))) * 8];
      }
    }
#pragma unroll
    for (int ks = 0; ks < 2; ks++)
#pragma unroll
      for (int m = 0; m < MF; m++)
#pragma unroll
        for (int n = 0; n < NF; n++)
          acc[m][n] = __builtin_amdgcn_mfma_f32_16x16x32_bf16(af[ks][m], bfr[ks][n], acc[m][n], 0, 0, 0);
    __syncthreads();
    buf ^= 1;
  }

  if constexpr (VAR == 0) {            // A0 = x@Wx + bias (3 gates), f32 row-major out
#pragma unroll
    for (int m = 0; m < MF; m++)
#pragma unroll
      for (int n = 0; n < NF; n++)
#pragma unroll
        for (int i = 0; i < 4; i++) {
          int row = bm * BM + wm * WM + m * 16 + lg * 4 + i;
          int col = bn * BN + wn * WN + n * 16 + lr;
          if (col >= p.N) continue;
          float bias = col < 512 ? p.bias0[col] : (col < 1024 ? p.bias1[col - 512] : p.bias2[col - 1024]);
          p.fdst[(size_t)row * 1536 + col] = acc[m][n][i] + bias;
        }
  } else {                             // VAR 5: logits -> smem transpose -> float4 full-line stores
    float* fs = (float*)smem;          // 128x128 f32 = 64 KiB
#pragma unroll
    for (int m = 0; m < MF; m++)
#pragma unroll
      for (int n = 0; n < NF; n++)
#pragma unroll
        for (int i = 0; i < 4; i++) {
          int lrow = wm * WM + m * 16 + lg * 4 + i;
          int lcol = wn * WN + n * 16 + lr;
          int col = bn * BN + lcol;
          fs[lrow * 128 + lcol] = acc[m][n][i] + (col < p.N ? p.bout[col] : 0.f);
        }
    __syncthreads();
#pragma unroll
    for (int j = 0; j < 16; j++) {
      int idx = j * 256 + tid;         // 0..4095 float4 slots
      int r = idx >> 5, c4 = (idx & 31) << 2;
      int gr = bm * BM + r;
      int tt = gr >> 7, b = gr & 127;
      int col = bn * BN + c4;
      if (col < p.N) {
        f32x4 v = *(const f32x4*)&fs[r * 128 + c4];
        *(f32x4*)&p.outp[((size_t)b * T_ + tt) * V_ + col] = v;
      }
    }
    __syncthreads();                   // smem reused across tiles
  }
}

template<int BM, int BN, int VAR>
__global__ __launch_bounds__(256) void gemm_one(GP p) {
  __shared__ short smem[2 * BM * 64 + 2 * BN * 64];
  gemm_core<BM, BN, VAR>(p, smem, smem + 2 * BM * 64, blockIdx.y, blockIdx.x, smem);
}

// ---------------- streaming row-local GEMM: A (16 rows) in LDS, B (weights) streamed ----------------
// Pipeline shape identical to the verified kcompute: 8-load chunks, DEPTH=3, 4 slots,
// vmcnt ladder {16,8,0}, sched_barrier after wait. MUST be entered right after a
// __syncthreads() (compiler drains vmcnt to 0 there) so counts are exact.
template<int NT, int NKS, bool SPLIT>
__device__ __forceinline__ void sgemm(const short* __restrict__ aL0, const short* __restrict__ aL1,
                                      const short* __restrict__ Wt, int wv, int lane, f32x4* acc) {
  const int lr = lane & 15, lg = lane >> 4;
  constexpr int K = NKS * 32;
  constexpr int NCH = NT * NKS / 8;
  constexpr int DEPTH = 3;
  bf16x8 bs[4][8];
#pragma unroll
  for (int c = 0; c < DEPTH; c++)
#pragma unroll
    for (int j = 0; j < 8; j++) {
      int l = c * 8 + j;
      int n = l % NT, ksg = l / NT;
      int c0 = ((n & 8) ? 512 : 0) + wv * 128 + (n & 7) * 16;
      ncload16(&bs[c & 3][j], Wt + (size_t)(c0 + lr) * K + ksg * 32 + lg * 8);
    }
#pragma unroll
  for (int c = 0; c < NCH; c++) {
    const int issued = (DEPTH + c < NCH) ? DEPTH + c : NCH;
    vwait_n((issued - c - 1) * 8);
    __builtin_amdgcn_sched_barrier(0);
    const int ksg = (c * 8) / NT;               // constant within chunk (8 <= NT)
    const short* ab = (SPLIT && ksg >= NKS / 2) ? aL1 : aL0;
    const int ksl = (SPLIT && ksg >= NKS / 2) ? ksg - NKS / 2 : ksg;
    bf16x8 af = *(const bf16x8*)&ab[(lr << 9) + ((((ksl << 2) + lg) ^ (lr & 7)) << 3)];
#pragma unroll
    for (int j = 0; j < 8; j++) {
      int n = (c * 8 + j) % NT;
      acc[n] = __builtin_amdgcn_mfma_f32_16x16x32_bf16(af, bs[c & 3][j], acc[n], 0, 0, 0);
    }
    if (DEPTH + c < NCH) {
      const int nc = DEPTH + c;
#pragma unroll
      for (int j = 0; j < 8; j++) {
        int l = nc * 8 + j;
        int n = l % NT, k2 = l / NT;
        int c0 = ((n & 8) ? 512 : 0) + wv * 128 + (n & 7) * 16;
        ncload16(&bs[nc & 3][j], Wt + (size_t)(c0 + lr) * K + k2 * 32 + lg * 8);
      }
    }
  }
}

// ---------------- persistent row-local recurrence + fused logits ----------------
struct RP {
  short *h0g, *H1all;
  const float *A0, *ihs0, *ihs1;
  const short *Whur0T, *Whc0T, *W1urT, *Wc1T;
  const float *bu1, *br1, *bc1;
  const short *WoutT; const float *bout;
  float *outp;
  int *bar;
};

// Roles by blockIdx (assumes bid%8 -> XCD round-robin; perf-only assumption):
//  bid<64, bid%8==0 : L0 group g=bid>>3 (all on XCD0; 1.5MB weights L2-resident; NO external waits)
//  bid<64, bid%8==1 : L1 group g=bid>>3 (XCD1; 3MB weights; waits only flag0[g] >= s+1)
//  bid%8>=2         : logits worker (XCDs 2-7; waits all flag1 >= t+1)
//  else             : idle
__global__ __launch_bounds__(256, 1) void recurrence(RP p) {
  __shared__ short smem[32768];   // 64 KiB
  const int bid = blockIdx.x, r8 = bid & 7;
  const int tid = threadIdx.x, wv = tid >> 6, lane = tid & 63;
  const int lr = lane & 15, lg = lane >> 4;
  int* bar = p.bar;

  if (bid < 64 && r8 == 0) {
    // ================= L0: rows r0..r0+15, zero external waits =================
    const int g = bid >> 3, r0 = g * 16;
    short* hA  = smem;           // [16][512] bf16, swizzled
    short* rhA = smem + 8192;
    float hreg[8][4];
#pragma unroll
    for (int n = 0; n < 8; n++)
#pragma unroll
      for (int i = 0; i < 4; i++) {
        int row = lg * 4 + i, col = wv * 128 + n * 16 + lr;
        float v = p.ihs0[(r0 + row) * 512 + col];
        hreg[n][i] = v;
        hA[swz(row, col)] = f2bf(v);
      }
    __syncthreads();
    for (int s = 0; s < T_; s++) {
      f32x4 ag[16] = {};
      sgemm<16, 16, false>(hA, hA, p.Whur0T, wv, lane, ag);
      const float* a0 = p.A0 + (size_t)(s * 128 + r0) * 1536;
      f32x4 uv[8];
#pragma unroll
      for (int n = 0; n < 8; n++)
#pragma unroll
        for (int i = 0; i < 4; i++) {
          int row = lg * 4 + i, col = wv * 128 + n * 16 + lr;
          uv[n][i] = sigm(ag[n][i] + a0[row * 1536 + col]);
          float rr = sigm(ag[8 + n][i] + a0[row * 1536 + 512 + col]);
          rhA[swz(row, col)] = f2bf(rr * hreg[n][i]);
        }
      __syncthreads();
      f32x4 ac[8] = {};
      sgemm<8, 16, false>(rhA, rhA, p.Whc0T, wv, lane, ac);
      short* hg = p.h0g + ((size_t)s * 8 + g) * 8192;
#pragma unroll
      for (int n = 0; n < 8; n++)
#pragma unroll
        for (int i = 0; i < 4; i++) {
          int row = lg * 4 + i, col = wv * 128 + n * 16 + lr;
          float c = tanhfast(ac[n][i] + a0[row * 1536 + 1024 + col]);
          float hn = uv[n][i] * hreg[n][i] + (1.f - uv[n][i]) * c;
          hreg[n][i] = hn;
          short hb = f2bf(hn);
          hA[swz(row, col)] = hb;                       // gates done reading hA this step
          cstores(&hg[swz(row, col)], hb);              // pre-swizzled for L1's linear stage
          if (s == T_ - 1) p.outp[32000000 + (size_t)(r0 + row) * 512 + col] = hn;
        }
      setflag(bar, 0, g, s + 1);   // vwait0 + syncthreads inside (also fences hA for next step)
    }
  } else if (bid < 64 && r8 == 1) {
    // ================= L1: rows r0..r0+15, waits only on partner L0 =================
    const int g = bid >> 3, r0 = g * 16;
    short* bufH0  = smem;            // h0(s), staged from global (content pre-swizzled)
    short* bufH1  = smem + 8192;     // h1(s-1) bf16, swizzled
    short* bufRH1 = smem + 16384;    // r*h1 bf16, swizzled
    float hreg[8][4];
#pragma unroll
    for (int n = 0; n < 8; n++)
#pragma unroll
      for (int i = 0; i < 4; i++) {
        int row = lg * 4 + i, col = wv * 128 + n * 16 + lr;
        float v = p.ihs1[(r0 + row) * 512 + col];
        hreg[n][i] = v;
        bufH1[swz(row, col)] = f2bf(v);
      }
    __syncthreads();
    for (int s = 0; s < T_; s++) {
      waitwords(&bar[g], 1, s + 1);
      const char* srcb = (const char*)(p.h0g + ((size_t)s * 8 + g) * 8192);
#pragma unroll
      for (int j = 0; j < 4; j++)
        gload_lds16(srcb + j * 4096 + wv * 1024 + lane * 16,
                    (char*)bufH0 + j * 4096 + wv * 1024);
      vwait0();
      __syncthreads();
      f32x4 ag[16] = {};
      sgemm<16, 32, true>(bufH0, bufH1, p.W1urT, wv, lane, ag);
      f32x4 uv[8];
#pragma unroll
      for (int n = 0; n < 8; n++)
#pragma unroll
        for (int i = 0; i < 4; i++) {
          int row = lg * 4 + i, col = wv * 128 + n * 16 + lr;
          uv[n][i] = sigm(ag[n][i] + p.bu1[col]);
          float rr = sigm(ag[8 + n][i] + p.br1[col]);
          bufRH1[swz(row, col)] = f2bf(rr * hreg[n][i]);
        }
      __syncthreads();
      f32x4 ac[8] = {};
      sgemm<8, 32, true>(bufH0, bufRH1, p.Wc1T, wv, lane, ac);
#pragma unroll
      for (int n = 0; n < 8; n++)
#pragma unroll
        for (int i = 0; i < 4; i++) {
          int row = lg * 4 + i, col = wv * 128 + n * 16 + lr;
          float c = tanhfast(ac[n][i] + p.bc1[col]);
          float hn = uv[n][i] * hreg[n][i] + (1.f - uv[n][i]) * c;
          hreg[n][i] = hn;
          short hb = f2bf(hn);
          bufH1[swz(row, col)] = hb;
          cstores(&p.H1all[(size_t)s * 65536 + (r0 + row) * 512 + col], hb);
          if (s == T_ - 1) p.outp[32000000 + 65536 + (size_t)(r0 + row) * 512 + col] = hn;
        }
      setflag(bar, 1, g, s + 1);
    }
  } else if (r8 >= 2) {
    // ================= logits workers (192), gated on L1 step flags =================
    const int w = (bid < 64) ? (6 * (bid >> 3) + r8 - 2)
                             : (48 + 6 * ((bid - 64) >> 3) + r8 - 2);
    GP gq = {};
    gq.A = p.H1all; gq.lda = 512; gq.Bt = p.WoutT; gq.ldb = 512; gq.N = V_; gq.K = 512;
    gq.outp = p.outp; gq.bout = p.bout;
    int done_t = 0;
    for (int idx = w; idx < 79 * T_; idx += 192) {
      int t = idx / 79, bn = idx % 79;
      if (t + 1 > done_t) { waitwords(&bar[256], 8, t + 1); done_t = t + 1; }
      gemm_core<128, 128, 5>(gq, smem, smem + 16384, t, bn, smem);
    }
  }
}

// ---------------- host ----------------
extern "C" void kernel_launch(void* const* d_in, const int* in_sizes, int n_in,
                              void* d_out, int out_size, void* d_ws, size_t ws_size,
                              hipStream_t stream) {
  const int*   tokens = (const int*)  d_in[0];
  const float* cnn    = (const float*)d_in[1];
  const float* ihs    = (const float*)d_in[2];
  const float* emb    = (const float*)d_in[3];
  const float* Wu0 = (const float*)d_in[4];
  const float* Wr0 = (const float*)d_in[5];
  const float* Wc0 = (const float*)d_in[6];
  const float* bu0 = (const float*)d_in[7];
  const float* br0 = (const float*)d_in[8];
  const float* bc0 = (const float*)d_in[9];
  const float* Wu1 = (const float*)d_in[10];
  const float* Wr1 = (const float*)d_in[11];
  const float* Wc1 = (const float*)d_in[12];
  const float* bu1 = (const float*)d_in[13];
  const float* br1 = (const float*)d_in[14];
  const float* bc1 = (const float*)d_in[15];
  const float* Wout = (const float*)d_in[16];
  const float* bout = (const float*)d_in[17];
  float* out = (float*)d_out;

  char* w = (char*)d_ws;
  size_t off = 0;
  auto alloc = [&](size_t bytes) { void* p = w + off; off += (bytes + 255) & ~255ull; return p; };
  short* WxT    = (short*)alloc(1536 * 1024 * 2);
  short* Whur0T = (short*)alloc(1024 * 512 * 2);
  short* Whc0T  = (short*)alloc(512 * 512 * 2);
  short* W1urT  = (short*)alloc(1024 * 1024 * 2);
  short* Wc1T   = (short*)alloc(512 * 1024 * 2);
  short* WoutT  = (short*)alloc((size_t)10000 * 512 * 2);
  short* X0     = (short*)alloc((size_t)3200 * 1024 * 2);
  float* A0     = (float*)alloc((size_t)3200 * 1536 * 4);
  short* H1all  = (short*)alloc((size_t)3200 * 512 * 2);
  short* h0g    = (short*)alloc((size_t)25 * 8 * 8192 * 2);   // per (step, group) h0 slices, pre-swizzled
  int*   bar    = (int*)alloc(4096);
  (void)ws_size; (void)in_sizes; (void)n_in; (void)out_size;

  {
    TJobs J;
    J.j[0] = { Wu0,              WxT,                1024, 512,  0    };
    J.j[1] = { Wr0,              WxT + 512 * 1024,   1024, 512,  512  };
    J.j[2] = { Wc0,              WxT + 1024 * 1024,  1024, 512,  1024 };
    J.j[3] = { Wu0 + 1024 * 512, Whur0T,             512,  512,  1536 };
    J.j[4] = { Wr0 + 1024 * 512, Whur0T + 512 * 512, 512,  512,  1792 };
    J.j[5] = { Wc0 + 1024 * 512, Whc0T,              512,  512,  2048 };
    J.j[6] = { Wu1,              W1urT,              1024, 512,  2304 };
    J.j[7] = { Wr1,              W1urT + 512 * 1024, 1024, 512,  2816 };
    J.j[8] = { Wc1,              Wc1T,               1024, 512,  3328 };
    J.j[9] = { Wout,             WoutT,              512,  10000, 3840 };
    tcast_all<<<8848, dim3(32, 8), 0, stream>>>(J);
  }

  build_x0<<<3200, 256, 0, stream>>>(tokens, emb, cnn, X0);
  hipMemsetAsync(bar, 0, 4096, stream);   // flags monotone per dispatch: re-zero every call

  // A0 = X0 @ WxT^T + biases : [3200,1536] f32
  {
    GP g = {};
    g.A = X0; g.lda = 1024; g.Bt = WxT; g.ldb = 1024; g.N = 1536; g.K = 1024;
    g.bias0 = bu0; g.bias1 = br0; g.bias2 = bc0; g.fdst = A0;
    gemm_one<128, 128, 0><<<dim3(12, 25), 256, 0, stream>>>(g);
  }

  // persistent row-local recurrence + fused logits
  {
    RP r = {};
    r.h0g = h0g; r.H1all = H1all;
    r.A0 = A0; r.ihs0 = ihs; r.ihs1 = ihs + 65536;
    r.Whur0T = Whur0T; r.Whc0T = Whc0T; r.W1urT = W1urT; r.Wc1T = Wc1T;
    r.bu1 = bu1; r.br1 = br1; r.bc1 = bc1;
    r.WoutT = WoutT; r.bout = bout;
    r.outp = out;
    r.bar = bar;
    recurrence<<<dim3(256), 256, 0, stream>>>(r);
  }
}

// Round 15
// 522.393 us; speedup vs baseline: 10.6441x; 10.6441x over previous
//
#include <hip/hip_runtime.h>

#define T_ 25
#define V_ 10000
#define NWG_ 256

#define R_P3 0
#define R_P1 1
#define R_P4 2
#define R_P2 3

typedef short bf16x8 __attribute__((ext_vector_type(8)));
typedef float f32x4 __attribute__((ext_vector_type(4)));

__device__ __forceinline__ short f2bf(float x) {
  union { float f; unsigned u; } v; v.f = x;
  unsigned r = (v.u + 0x7fffu + ((v.u >> 16) & 1u)) >> 16;
  return (short)r;
}
__device__ __forceinline__ float sigm(float z) { return 1.f / (1.f + __expf(-z)); }
__device__ __forceinline__ float tanhfast(float z) {
  float e = __expf(2.f * z);
  return 1.f - 2.f / (e + 1.f);
}

__device__ __forceinline__ void gload_lds16(const void* g, void* l) {
  __builtin_amdgcn_global_load_lds((const __attribute__((address_space(1))) void*)g,
                                   (__attribute__((address_space(3))) void*)l, 16, 0, 0);
}

__device__ __forceinline__ void vwait0() { asm volatile("s_waitcnt vmcnt(0)" ::: "memory"); }
__device__ __forceinline__ void vwait_n(int n) {   // n folds to constant after unroll
  switch (n) {
    case 0:  asm volatile("s_waitcnt vmcnt(0)"  ::: "memory"); break;
    case 8:  asm volatile("s_waitcnt vmcnt(8)"  ::: "memory"); break;
    case 16: asm volatile("s_waitcnt vmcnt(16)" ::: "memory"); break;
    default: asm volatile("s_waitcnt vmcnt(0)"  ::: "memory"); break;
  }
}
// cached load (L2-allocating): safe on step-rotated buffers (fresh addresses each step)
__device__ __forceinline__ void ncload16(bf16x8* d, const short* p) {
  asm volatile("global_load_dwordx4 %0, %1, off" : "=v"(*d) : "v"(p) : "memory");
}
// coherent write-through stores: land at IC, no dirty L2 lines anywhere
__device__ __forceinline__ void cstoref(float* p, float v) {
  asm volatile("global_store_dword %0, %1, off sc0 sc1" :: "v"(p), "v"(v) : "memory");
}
__device__ __forceinline__ void cstores(short* p, int v) {
  asm volatile("global_store_short %0, %1, off sc0 sc1" :: "v"(p), "v"(v) : "memory");
}

// MFMA-A-fragment-linear layout: value (row, col) lives at
// blk = (col>>5)*8 + (row>>4); lane = (row&15) | (((col>>3)&3)<<4); elem = col&7
__device__ __forceinline__ int FL(int row, int col) {
  return (((col >> 5) * 8 + (row >> 4)) << 9) | (((row & 15) | (((col >> 3) & 3) << 4)) << 3) | (col & 7);
}

// -------- p2p sync: per-WG done-word flags (no RMW), packed 4B stride --------
// flag word = bar[role*256 + wg]. Producer: drain -> one sc0sc1 store of (s+1).
// Consumer: wave 0 does ONE wave-wide vector load (lane -> producer WG) + __all.
__device__ __forceinline__ void setflag(int* bar, int role, int wg, int val) {
  vwait0();                        // every wave drains its own coherent stores
  __syncthreads();                 // all waves of the WG done
  if (threadIdx.x == 0) {
    int* wp = bar + role * 256 + wg;
    asm volatile("global_store_dword %0, %1, off sc0 sc1" :: "v"(wp), "v"(val) : "memory");
  }
}
__device__ __forceinline__ void waitflag(int* bar, int role, int cnt, int need) {
  if (threadIdx.x < 64) {          // wave 0 polls; lanes cover all producer WGs
    int idx = (int)threadIdx.x < cnt ? (int)threadIdx.x : cnt - 1;
    const int* wp = bar + role * 256 + idx;
    for (;;) {
      int v;
      asm volatile("global_load_dword %0, %1, off sc0 sc1" : "=v"(v) : "v"(wp) : "memory");
      asm volatile("s_waitcnt vmcnt(0)" ::: "memory");
      if (__all(v >= need)) break;
      __builtin_amdgcn_s_sleep(1);
    }
  }
  __syncthreads();
}

// ---------------- merged transpose + cast f32[R,C] -> bf16[C,R] ----------------
struct TJob { const float* src; short* dst; int R, C, t0; };
struct TJobs { TJob j[10]; };

__global__ void tcast_all(TJobs J) {
  __shared__ float t[32][33];
  int bid = blockIdx.x;
  int ji = 0;
  while (ji < 9 && bid >= J.j[ji + 1].t0) ji++;
  const float* src = J.j[ji].src;
  short* dst = J.j[ji].dst;
  int R = J.j[ji].R, C = J.j[ji].C;
  int rel = bid - J.j[ji].t0;
  int ctiles = (C + 31) >> 5;
  int rt0 = (rel / ctiles) * 32, ct0 = (rel % ctiles) * 32;
  int tx = threadIdx.x, ty = threadIdx.y; // 32x8
#pragma unroll
  for (int i = 0; i < 4; i++) {
    int r = rt0 + ty + i * 8, c = ct0 + tx;
    if (r < R && c < C) t[ty + i * 8][tx] = src[(size_t)r * C + c];
  }
  __syncthreads();
#pragma unroll
  for (int i = 0; i < 4; i++) {
    int c = ct0 + ty + i * 8, r = rt0 + tx;
    if (r < R && c < C) dst[(size_t)c * R + r] = f2bf(t[tx][ty + i * 8]);
  }
}

// ---------------- build X0 [T*B, 1024] bf16 : [emb(tok) | cnn] ----------------
__global__ void build_x0(const int* __restrict__ tok, const float* __restrict__ emb,
                         const float* __restrict__ cnn, short* __restrict__ X0) {
  int row = blockIdx.x;           // t*128 + b
  int t = row >> 7, b = row & 127;
  int tk = tok[b * T_ + t];
  const float* er = emb + (size_t)tk * 512;
  short* dst = X0 + (size_t)row * 1024;
  for (int i = threadIdx.x; i < 1024; i += 256)
    dst[i] = f2bf(i < 512 ? er[i] : cnn[b * 512 + (i - 512)]);
}

// ---------------- init: H[0] = [h0(-1) | h1(-1)] in FL layout; h0b[0], h1b[0] ----------------
__global__ void init_h(const float* __restrict__ ihs, float* h0f0, float* h1f0, short* H0) {
  int i = blockIdx.x * 256 + threadIdx.x;  // i = b*512 + h
  if (i < 65536) {
    int b = i >> 9, h = i & 511;
    float v0 = ihs[i], v1 = ihs[65536 + i];
    h0f0[i] = v0; h1f0[i] = v1;
    H0[FL(b, h)] = f2bf(v0);
    H0[FL(b, 512 + h)] = f2bf(v1);
  }
}

// ---------------- big MFMA GEMM core (A0 precompute + logits tiles) ----------------
struct GP {
  const short* A; const short* Bt;
  int lda, ldb, N, K;
  const float* bias0; const float* bias1; const float* bias2;
  float* fdst;
  float* outp; const float* bout;
};

template<int BM, int BN, int VAR>
__device__ __forceinline__ void gemm_core(const GP& p, short* la, short* lb, int bm, int bn, short* smem) {
  const int tid = threadIdx.x;
  const int wave = tid >> 6, lane = tid & 63;
  const int wm = wave >> 1, wn = wave & 1;
  constexpr int WM = BM / 2, WN = BN / 2;
  constexpr int MF = WM / 16, NF = WN / 16;
  const int lr = lane & 15, lg = lane >> 4;
  const short* Abase = p.A + (size_t)bm * BM * p.lda;
  const short* Bbase = p.Bt + (size_t)bn * BN * p.ldb;
  const int bnmax = p.N - bn * BN;
  f32x4 acc[MF][NF] = {};
  const int nkb = p.K >> 6;

  auto stA = [&](int buf, int k0) {
    constexpr int NI = BM / 32;
#pragma unroll
    for (int j = 0; j < NI; j++) {
      int glin = j * 256 + tid;
      int row = glin >> 3, gc = glin & 7;
      int gcs = gc ^ (row & 7);
      gload_lds16(Abase + (size_t)row * p.lda + k0 + gcs * 8,
                  &la[buf * BM * 64 + j * 2048 + wave * 512]);
    }
  };
  auto stB = [&](int buf, int k0) {
    constexpr int NI = BN / 32;
#pragma unroll
    for (int j = 0; j < NI; j++) {
      int glin = j * 256 + tid;
      int row = glin >> 3, gc = glin & 7;
      int gcs = gc ^ (row & 7);
      int rc = row < bnmax ? row : bnmax - 1;
      gload_lds16(Bbase + (size_t)rc * p.ldb + k0 + gcs * 8,
                  &lb[buf * BN * 64 + j * 2048 + wave * 512]);
    }
  };

  stA(0, 0); stB(0, 0);
  __syncthreads();
  int buf = 0;
  for (int kb = 0; kb < nkb; kb++) {
    if (kb + 1 < nkb) { stA(buf ^ 1, (kb + 1) * 64); stB(buf ^ 1, (kb + 1) * 64); }
    bf16x8 af[2][MF], bfr[2][NF];
#pragma unroll
    for (int ks = 0; ks < 2; ks++) {
#pragma unroll
      for (int m = 0; m < MF; m++) {
        int ar = wm * WM + m * 16 + lr;
        af[ks][m] = *(const bf16x8*)&la[buf * BM * 64 + (ar * 8 + ((ks * 4 + lg) ^ (ar & 7))) * 8];
      }
#pragma unroll
      for (int n = 0; n < NF; n++) {
        int br = wn * WN + n * 16 + lr;
        bfr[ks][n] = *(const bf16x8*)&lb[buf * BN * 64 + (br * 8 + ((ks * 4 + lg) ^ (br & 7))) * 8];
      }
    }
#pragma unroll
    for (int ks = 0; ks < 2; ks++)
#pragma unroll
      for (int m = 0; m < MF; m++)
#pragma unroll
        for (int n = 0; n < NF; n++)
          acc[m][n] = __builtin_amdgcn_mfma_f32_16x16x32_bf16(af[ks][m], bfr[ks][n], acc[m][n], 0, 0, 0);
    __syncthreads();
    buf ^= 1;
  }

  if constexpr (VAR == 0) {            // A0 = x@Wx + bias (3 gates), f32 row-major out
#pragma unroll
    for (int m = 0; m < MF; m++)
#pragma unroll
      for (int n = 0; n < NF; n++)
#pragma unroll
        for (int i = 0; i < 4; i++) {
          int row = bm * BM + wm * WM + m * 16 + lg * 4 + i;
          int col = bn * BN + wn * WN + n * 16 + lr;
          if (col >= p.N) continue;
          float bias = col < 512 ? p.bias0[col] : (col < 1024 ? p.bias1[col - 512] : p.bias2[col - 1024]);
          p.fdst[(size_t)row * 1536 + col] = acc[m][n][i] + bias;
        }
  } else {                             // VAR 5: logits -> smem transpose -> float4 full-line stores
    float* fs = (float*)smem;          // 128x128 f32 = 64 KiB
#pragma unroll
    for (int m = 0; m < MF; m++)
#pragma unroll
      for (int n = 0; n < NF; n++)
#pragma unroll
        for (int i = 0; i < 4; i++) {
          int lrow = wm * WM + m * 16 + lg * 4 + i;
          int lcol = wn * WN + n * 16 + lr;
          int col = bn * BN + lcol;
          fs[lrow * 128 + lcol] = acc[m][n][i] + (col < p.N ? p.bout[col] : 0.f);
        }
    __syncthreads();
#pragma unroll
    for (int j = 0; j < 16; j++) {
      int idx = j * 256 + tid;         // 0..4095 float4 slots
      int r = idx >> 5, c4 = (idx & 31) << 2;
      int gr = bm * BM + r;
      int tt = gr >> 7, b = gr & 127;
      int col = bn * BN + c4;
      if (col < p.N) {
        f32x4 v = *(const f32x4*)&fs[r * 128 + c4];
        *(f32x4*)&p.outp[((size_t)b * T_ + tt) * V_ + col] = v;
      }
    }
    __syncthreads();                   // smem reused across tiles by R_LOG
  }
}

template<int BM, int BN, int VAR>
__global__ __launch_bounds__(256) void gemm_one(GP p) {
  __shared__ short smem[2 * BM * 64 + 2 * BN * 64];
  gemm_core<BM, BN, VAR>(p, smem, smem + 2 * BM * 64, blockIdx.y, blockIdx.x, smem);
}

// ---------------- persistent recurrence kernel (step-rotated buffers + fused logits) ----------------
struct RP {
  short *Hb, *XCb, *RHb, *H1all;   // H: 26 x 131072 shorts; XC: 25 x 131072; RH: 25 x 65536
  float *u0b, *u1b, *h0b, *h1b;    // u: 25 x 65536 f32; h: 26 x 65536 f32
  const float *A0;
  const short *Whur0T, *Whc0T, *W1urT, *Wc1T;
  const float *bu1, *br1, *bc1;
  const short *WoutT; const float *bout;
  float *outp;
  int *bar;
};

template<int NKS>
__device__ __forceinline__ void wload(const short* __restrict__ Wt, int n0, int lane, bf16x8* wfr) {
  const short* p = Wt + (size_t)(n0 + (lane & 15)) * (NKS * 32) + ((lane >> 4) * 8);
#pragma unroll
  for (int ks = 0; ks < NKS; ks++) wfr[ks] = *(const bf16x8*)(p + (size_t)ks * 32);
}

// A-read via cached loads, 3-deep counted-vmcnt pipeline (chunk = 4 k-slices = 8 loads).
// SPLIT: slices [0,NKS/2) from Alo, [NKS/2,NKS) from Ahi (P3's A spans H[s+1].lo | H[s].hi).
template<int NKS, bool SPLIT>
__device__ __forceinline__ void kcompute(const short* __restrict__ Alo, const short* __restrict__ Ahi,
                                         int rb0, int lane, const bf16x8* __restrict__ wfr, f32x4* acc) {
  const short* aplo = Alo + rb0 * 512 + lane * 8;
  const short* aphi = Ahi + rb0 * 512 + lane * 8;
  constexpr int NCH = NKS / 4;
  constexpr int DEPTH = NCH < 3 ? NCH : 3;
  bf16x8 s0[4][4], s1[4][4];
#pragma unroll
  for (int c = 0; c < DEPTH; c++)
#pragma unroll
    for (int j = 0; j < 4; j++) {
      int ks = c * 4 + j;
      const short* ap = (SPLIT && ks >= NKS / 2) ? aphi : aplo;
      ncload16(&s0[c & 3][j], ap + ks * 4096);
      ncload16(&s1[c & 3][j], ap + ks * 4096 + 512);
    }
#pragma unroll
  for (int c = 0; c < NCH; c++) {
    const int issued = (DEPTH + c < NCH) ? DEPTH + c : NCH;
    vwait_n((issued - c - 1) * 8);
    __builtin_amdgcn_sched_barrier(0);
#pragma unroll
    for (int j = 0; j < 4; j++) {
      int ks = c * 4 + j;
      acc[ks & 1]       = __builtin_amdgcn_mfma_f32_16x16x32_bf16(s0[c & 3][j], wfr[ks], acc[ks & 1], 0, 0, 0);
      acc[2 + (ks & 1)] = __builtin_amdgcn_mfma_f32_16x16x32_bf16(s1[c & 3][j], wfr[ks], acc[2 + (ks & 1)], 0, 0, 0);
    }
    if (DEPTH + c < NCH) {
      const int nc = DEPTH + c;
#pragma unroll
      for (int j = 0; j < 4; j++) {
        int ks = nc * 4 + j;
        const short* ap = (SPLIT && ks >= NKS / 2) ? aphi : aplo;
        ncload16(&s0[nc & 3][j], ap + ks * 4096);
        ncload16(&s1[nc & 3][j], ap + ks * 4096 + 512);
      }
    }
  }
}

// Data-only hazards (rotation removed all WARs); per-WG flags = completed steps:
//  P3(s): all P2 flags >= s+1 [H[s+1].lo], all P4 flags >= s [H[s].hi, h1b[s], s>=1]
//  P1(s): all P2 flags >= s   [H[s].lo, h0b[s], s>=1]
//  P4(s): all P3 flags >= s+1 [xc[s].hi, u1b[s]], all P2 flags >= s+1 [xc[s].lo]
//  P2(s): all P1 flags >= s+1 [u0b[s], rh0b[s]]
//  R_LOG tile(t,bn): all P4 flags >= t+1 [H1all[t]]
__global__ __launch_bounds__(256, 1) void recurrence(RP p) {
  __shared__ short smem[2 * 128 * 64 + 2 * 128 * 64];   // used by R_LOG only (64 KiB)
  const int bid = blockIdx.x;
  int* bar = p.bar;
  const int tid = threadIdx.x, wv = tid >> 6, lane = tid & 63;
  const int lr = lane & 15, lg = lane >> 4;

  if (bid >= 192) {
    // ---- R_LOG: logits tiles, gated on P4 step flags ----
    const int w = bid - 192;
    GP g = {};
    g.A = p.H1all; g.lda = 512; g.Bt = p.WoutT; g.ldb = 512; g.N = V_; g.K = 512;
    g.outp = p.outp; g.bout = p.bout;
    int done_t = 0;
    for (int idx = w; idx < 79 * 25; idx += 64) {
      int t = idx / 79, bn = idx % 79;
      if (t + 1 > done_t) { waitflag(bar, R_P4, 32, t + 1); done_t = t + 1; }
      gemm_core<128, 128, 5>(g, smem, smem + 2 * 128 * 64, t, bn, smem);
    }
    return;
  }

  const int m8 = bid & 7;
  const int k = ((bid & 127) >> 3) * 4 + (m8 & 3);   // role-pinned: P3/P4 on XCD 0-3, P1/P2 on 4-7
  const int role = (bid < 128) ? ((m8 < 4) ? R_P3 : R_P1) : ((m8 < 4) ? R_P4 : R_P2);
  const int nt = k >> 1, mh = k & 1;
  const int colb = nt * 32 + (wv & 1) * 16;
  const int rb0 = mh * 4 + (wv >> 1) * 2;
  const int col = colb + lr;

  if (role == R_P3) {
    // ---- layer-1 u,r gates: out[128,1024], K=1024, A = H[s+1].lo | H[s].hi ----
    bf16x8 wfr[32]; wload<32>(p.W1urT, colb, lane, wfr);
    for (int s = 0; s < T_; s++) {
      waitflag(bar, R_P2, 32, s + 1);
      if (s >= 1) waitflag(bar, R_P4, 32, s);
      const short* Hs1 = p.Hb + (size_t)(s + 1) * 131072;
      const short* Hs  = p.Hb + (size_t)s * 131072;
      f32x4 acc[4] = {};
      kcompute<32, true>(Hs1, Hs, rb0, lane, wfr, acc);
      f32x4 am[2] = { acc[0] + acc[1], acc[2] + acc[3] };
      short* xc = p.XCb + (size_t)s * 131072;
      const float* h1s = p.h1b + (size_t)s * 65536;
      float* u1s = p.u1b + (size_t)s * 65536;
#pragma unroll
      for (int m = 0; m < 2; m++)
#pragma unroll
        for (int i = 0; i < 4; i++) {
          int row = (rb0 + m) * 16 + lg * 4 + i;
          if (colb < 512) {
            cstoref(&u1s[row * 512 + col], sigm(am[m][i] + p.bu1[col]));
          } else {
            float sg = sigm(am[m][i] + p.br1[col - 512]);
            cstores(&xc[FL(row, col)], f2bf(sg * h1s[row * 512 + (col - 512)]));
          }
        }
      setflag(bar, R_P3, k, s + 1);
    }
  } else if (role == R_P1) {
    // ---- layer-0 u,r gates: out[128,1024], K=512, A = H[s].lo ----
    bf16x8 wfr[16]; wload<16>(p.Whur0T, colb, lane, wfr);
    for (int s = 0; s < T_; s++) {
      if (s >= 1) waitflag(bar, R_P2, 32, s);
      const short* Hs = p.Hb + (size_t)s * 131072;
      f32x4 acc[4] = {};
      kcompute<16, false>(Hs, Hs, rb0, lane, wfr, acc);
      f32x4 am[2] = { acc[0] + acc[1], acc[2] + acc[3] };
      const float* a0s = p.A0 + (size_t)s * 196608;
      const float* h0s = p.h0b + (size_t)s * 65536;
      float* u0s = p.u0b + (size_t)s * 65536;
      short* rh = p.RHb + (size_t)s * 65536;
#pragma unroll
      for (int m = 0; m < 2; m++)
#pragma unroll
        for (int i = 0; i < 4; i++) {
          int row = (rb0 + m) * 16 + lg * 4 + i;
          if (colb < 512) {
            cstoref(&u0s[row * 512 + col], sigm(am[m][i] + a0s[row * 1536 + col]));
          } else {
            float sg = sigm(am[m][i] + a0s[row * 1536 + col]);
            cstores(&rh[FL(row, col - 512)], f2bf(sg * h0s[row * 512 + (col - 512)]));
          }
        }
      setflag(bar, R_P1, k, s + 1);
    }
  } else if (role == R_P4) {
    // ---- layer-1 cand + h1 update: out[128,512], K=1024, A = xc[s] ----
    bf16x8 wfr[32]; wload<32>(p.Wc1T, colb, lane, wfr);
    for (int s = 0; s < T_; s++) {
      waitflag(bar, R_P3, 64, s + 1);
      waitflag(bar, R_P2, 32, s + 1);
      const short* xc = p.XCb + (size_t)s * 131072;
      f32x4 acc[4] = {};
      kcompute<32, false>(xc, xc, rb0, lane, wfr, acc);
      f32x4 am[2] = { acc[0] + acc[1], acc[2] + acc[3] };
      const float* u1s = p.u1b + (size_t)s * 65536;
      const float* h1s = p.h1b + (size_t)s * 65536;
      float* h1d = p.h1b + (size_t)(s + 1) * 65536;
      short* xh = p.Hb + (size_t)(s + 1) * 131072;
#pragma unroll
      for (int m = 0; m < 2; m++)
#pragma unroll
        for (int i = 0; i < 4; i++) {
          int row = (rb0 + m) * 16 + lg * 4 + i;
          float cc = tanhfast(am[m][i] + p.bc1[col]);
          float u = u1s[row * 512 + col], h = h1s[row * 512 + col];
          float hn = u * h + (1.f - u) * cc;
          cstoref(&h1d[row * 512 + col], hn);
          short hb = f2bf(hn);
          cstores(&xh[FL(row, 512 + col)], hb);
          cstores(&p.H1all[(size_t)s * 65536 + row * 512 + col], hb);  // read by R_LOG (IC-coherent)
          if (s == T_ - 1) p.outp[32000000 + 65536 + row * 512 + col] = hn;
        }
      setflag(bar, R_P4, k, s + 1);
    }
  } else {
    // ---- layer-0 cand + h0 update: out[128,512], K=512, A = rh0b[s] ----
    bf16x8 wfr[16]; wload<16>(p.Whc0T, colb, lane, wfr);
    for (int s = 0; s < T_; s++) {
      waitflag(bar, R_P1, 64, s + 1);
      const short* rh = p.RHb + (size_t)s * 65536;
      f32x4 acc[4] = {};
      kcompute<16, false>(rh, rh, rb0, lane, wfr, acc);
      f32x4 am[2] = { acc[0] + acc[1], acc[2] + acc[3] };
      const float* a0s = p.A0 + (size_t)s * 196608;
      const float* u0s = p.u0b + (size_t)s * 65536;
      const float* h0s = p.h0b + (size_t)s * 65536;
      float* h0d = p.h0b + (size_t)(s + 1) * 65536;
      short* xh  = p.Hb + (size_t)(s + 1) * 131072;
      short* xcw = p.XCb + (size_t)s * 131072;
#pragma unroll
      for (int m = 0; m < 2; m++)
#pragma unroll
        for (int i = 0; i < 4; i++) {
          int row = (rb0 + m) * 16 + lg * 4 + i;
          float c = tanhfast(am[m][i] + a0s[row * 1536 + 1024 + col]);
          float u = u0s[row * 512 + col], h = h0s[row * 512 + col];
          float hn = u * h + (1.f - u) * c;
          cstoref(&h0d[row * 512 + col], hn);
          short hb = f2bf(hn);
          cstores(&xh[FL(row, col)], hb);
          cstores(&xcw[FL(row, col)], hb);
          if (s == T_ - 1) p.outp[32000000 + row * 512 + col] = hn;
        }
      setflag(bar, R_P2, k, s + 1);
    }
  }
}

// ---------------- host ----------------
extern "C" void kernel_launch(void* const* d_in, const int* in_sizes, int n_in,
                              void* d_out, int out_size, void* d_ws, size_t ws_size,
                              hipStream_t stream) {
  const int*   tokens = (const int*)  d_in[0];
  const float* cnn    = (const float*)d_in[1];
  const float* ihs    = (const float*)d_in[2];
  const float* emb    = (const float*)d_in[3];
  const float* Wu0 = (const float*)d_in[4];
  const float* Wr0 = (const float*)d_in[5];
  const float* Wc0 = (const float*)d_in[6];
  const float* bu0 = (const float*)d_in[7];
  const float* br0 = (const float*)d_in[8];
  const float* bc0 = (const float*)d_in[9];
  const float* Wu1 = (const float*)d_in[10];
  const float* Wr1 = (const float*)d_in[11];
  const float* Wc1 = (const float*)d_in[12];
  const float* bu1 = (const float*)d_in[13];
  const float* br1 = (const float*)d_in[14];
  const float* bc1 = (const float*)d_in[15];
  const float* Wout = (const float*)d_in[16];
  const float* bout = (const float*)d_in[17];
  float* out = (float*)d_out;

  char* w = (char*)d_ws;
  size_t off = 0;
  auto alloc = [&](size_t bytes) { void* p = w + off; off += (bytes + 255) & ~255ull; return p; };
  short* WxT    = (short*)alloc(1536 * 1024 * 2);
  short* Whur0T = (short*)alloc(1024 * 512 * 2);
  short* Whc0T  = (short*)alloc(512 * 512 * 2);
  short* W1urT  = (short*)alloc(1024 * 1024 * 2);
  short* Wc1T   = (short*)alloc(512 * 1024 * 2);
  short* WoutT  = (short*)alloc((size_t)10000 * 512 * 2);
  short* X0     = (short*)alloc((size_t)3200 * 1024 * 2);
  float* A0     = (float*)alloc((size_t)3200 * 1536 * 4);
  short* H1all  = (short*)alloc((size_t)3200 * 512 * 2);
  // step-rotated state (fresh addresses per step -> cached reads are coherence-safe)
  short* Hb     = (short*)alloc((size_t)26 * 131072 * 2);
  short* XCb    = (short*)alloc((size_t)25 * 131072 * 2);
  short* RHb    = (short*)alloc((size_t)25 * 65536 * 2);
  float* u0b    = (float*)alloc((size_t)25 * 65536 * 4);
  float* u1b    = (float*)alloc((size_t)25 * 65536 * 4);
  float* h0b    = (float*)alloc((size_t)26 * 65536 * 4);
  float* h1b    = (float*)alloc((size_t)26 * 65536 * 4);
  int*   bar    = (int*)alloc(4096);
  (void)ws_size; (void)in_sizes; (void)n_in; (void)out_size;

  {
    TJobs J;
    J.j[0] = { Wu0,              WxT,                1024, 512,  0    };
    J.j[1] = { Wr0,              WxT + 512 * 1024,   1024, 512,  512  };
    J.j[2] = { Wc0,              WxT + 1024 * 1024,  1024, 512,  1024 };
    J.j[3] = { Wu0 + 1024 * 512, Whur0T,             512,  512,  1536 };
    J.j[4] = { Wr0 + 1024 * 512, Whur0T + 512 * 512, 512,  512,  1792 };
    J.j[5] = { Wc0 + 1024 * 512, Whc0T,              512,  512,  2048 };
    J.j[6] = { Wu1,              W1urT,              1024, 512,  2304 };
    J.j[7] = { Wr1,              W1urT + 512 * 1024, 1024, 512,  2816 };
    J.j[8] = { Wc1,              Wc1T,               1024, 512,  3328 };
    J.j[9] = { Wout,             WoutT,              512,  10000, 3840 };
    tcast_all<<<8848, dim3(32, 8), 0, stream>>>(J);
  }

  build_x0<<<3200, 256, 0, stream>>>(tokens, emb, cnn, X0);
  init_h<<<256, 256, 0, stream>>>(ihs, h0b, h1b, Hb);
  hipMemsetAsync(bar, 0, 4096, stream);   // flags are monotone per dispatch: re-zero every call

  // A0 = X0 @ WxT^T + biases : [3200,1536] f32
  {
    GP g = {};
    g.A = X0; g.lda = 1024; g.Bt = WxT; g.ldb = 1024; g.N = 1536; g.K = 1024;
    g.bias0 = bu0; g.bias1 = br0; g.bias2 = bc0; g.fdst = A0;
    gemm_one<128, 128, 0><<<dim3(12, 25), 256, 0, stream>>>(g);
  }

  // persistent recurrence + fused logits: 192 role WGs + 64 logits WGs
  {
    RP r = {};
    r.Hb = Hb; r.XCb = XCb; r.RHb = RHb; r.H1all = H1all;
    r.u0b = u0b; r.u1b = u1b; r.h0b = h0b; r.h1b = h1b;
    r.A0 = A0;
    r.Whur0T = Whur0T; r.Whc0T = Whc0T; r.W1urT = W1urT; r.Wc1T = Wc1T;
    r.bu1 = bu1; r.br1 = br1; r.bc1 = bc1;
    r.WoutT = WoutT; r.bout = bout;
    r.outp = out;
    r.bar = bar;
    recurrence<<<dim3(NWG_), 256, 0, stream>>>(r);
  }
}

// Round 16
// 518.372 us; speedup vs baseline: 10.7267x; 1.0078x over previous
//
#include <hip/hip_runtime.h>

#define T_ 25
#define V_ 10000
#define NWG_ 256

#define R_P3 0
#define R_P1 1
#define R_P4 2
#define R_P2 3

typedef short bf16x8 __attribute__((ext_vector_type(8)));
typedef float f32x4 __attribute__((ext_vector_type(4)));

__device__ __forceinline__ short f2bf(float x) {
  union { float f; unsigned u; } v; v.f = x;
  unsigned r = (v.u + 0x7fffu + ((v.u >> 16) & 1u)) >> 16;
  return (short)r;
}
__device__ __forceinline__ float sigm(float z) { return 1.f / (1.f + __expf(-z)); }
__device__ __forceinline__ float tanhfast(float z) {
  float e = __expf(2.f * z);
  return 1.f - 2.f / (e + 1.f);
}

__device__ __forceinline__ void gload_lds16(const void* g, void* l) {
  __builtin_amdgcn_global_load_lds((const __attribute__((address_space(1))) void*)g,
                                   (__attribute__((address_space(3))) void*)l, 16, 0, 0);
}

__device__ __forceinline__ void vwait0() { asm volatile("s_waitcnt vmcnt(0)" ::: "memory"); }
__device__ __forceinline__ void vwait_n(int n) {   // n folds to constant after unroll
  switch (n) {
    case 0:  asm volatile("s_waitcnt vmcnt(0)"  ::: "memory"); break;
    case 8:  asm volatile("s_waitcnt vmcnt(8)"  ::: "memory"); break;
    case 16: asm volatile("s_waitcnt vmcnt(16)" ::: "memory"); break;
    default: asm volatile("s_waitcnt vmcnt(0)"  ::: "memory"); break;
  }
}
// cached load (L2-allocating): safe on step-rotated buffers (fresh addresses each step)
__device__ __forceinline__ void ncload16(bf16x8* d, const short* p) {
  asm volatile("global_load_dwordx4 %0, %1, off" : "=v"(*d) : "v"(p) : "memory");
}
// coherent write-through stores: land at IC, no dirty L2 lines anywhere
__device__ __forceinline__ void cstoref(float* p, float v) {
  asm volatile("global_store_dword %0, %1, off sc0 sc1" :: "v"(p), "v"(v) : "memory");
}
__device__ __forceinline__ void cstores(short* p, int v) {
  asm volatile("global_store_short %0, %1, off sc0 sc1" :: "v"(p), "v"(v) : "memory");
}

// MFMA-A-fragment-linear layout: value (row, col) lives at
// blk = (col>>5)*8 + (row>>4); lane = (row&15) | (((col>>3)&3)<<4); elem = col&7
__device__ __forceinline__ int FL(int row, int col) {
  return (((col >> 5) * 8 + (row >> 4)) << 9) | (((row & 15) | (((col >> 3) & 3) << 4)) << 3) | (col & 7);
}

// -------- p2p sync: per-WG done-word flags (no RMW), packed 4B stride --------
// flag word = bar[role*256 + wg]. Producer: drain -> one sc0sc1 store of (s+1).
// Consumer: one wave does ONE wave-wide vector load (lane -> producer WG) + __all.
__device__ __forceinline__ void setflag(int* bar, int role, int wg, int val) {
  vwait0();                        // every wave drains its own coherent stores
  __syncthreads();                 // all waves of the WG done
  if (threadIdx.x == 0) {
    int* wp = bar + role * 256 + wg;
    asm volatile("global_store_dword %0, %1, off sc0 sc1" :: "v"(wp), "v"(val) : "memory");
  }
}
__device__ __forceinline__ void pollrole(const int* bar, int role, int cnt, int need, int lane) {
  int idx = lane < cnt ? lane : cnt - 1;
  const int* wp = bar + role * 256 + idx;
  for (;;) {
    int v;
    asm volatile("global_load_dword %0, %1, off sc0 sc1" : "=v"(v) : "v"(wp) : "memory");
    asm volatile("s_waitcnt vmcnt(0)" ::: "memory");
    if (__all(v >= need)) break;
    __builtin_amdgcn_s_sleep(1);
  }
}
__device__ __forceinline__ void waitflag(int* bar, int role, int cnt, int need) {
  if (threadIdx.x < 64) pollrole(bar, role, cnt, need, (int)threadIdx.x);
  __syncthreads();
}
// Concurrent two-role wait: wave 0 polls role A, wave 1 polls role B, join at barrier.
// Equivalent to two sequential waitflags (flags are monotone), minus one serial round-trip.
__device__ __forceinline__ void waitflag2(int* bar, int rA, int cA, int nA,
                                          int rB, int cB, int nB) {
  const int wvid = threadIdx.x >> 6, lane = threadIdx.x & 63;
  if (wvid == 0)      pollrole(bar, rA, cA, nA, lane);
  else if (wvid == 1) pollrole(bar, rB, cB, nB, lane);
  __syncthreads();
}

// ---------------- merged transpose + cast f32[R,C] -> bf16[C,R] ----------------
struct TJob { const float* src; short* dst; int R, C, t0; };
struct TJobs { TJob j[10]; };

__global__ void tcast_all(TJobs J) {
  __shared__ float t[32][33];
  int bid = blockIdx.x;
  int ji = 0;
  while (ji < 9 && bid >= J.j[ji + 1].t0) ji++;
  const float* src = J.j[ji].src;
  short* dst = J.j[ji].dst;
  int R = J.j[ji].R, C = J.j[ji].C;
  int rel = bid - J.j[ji].t0;
  int ctiles = (C + 31) >> 5;
  int rt0 = (rel / ctiles) * 32, ct0 = (rel % ctiles) * 32;
  int tx = threadIdx.x, ty = threadIdx.y; // 32x8
#pragma unroll
  for (int i = 0; i < 4; i++) {
    int r = rt0 + ty + i * 8, c = ct0 + tx;
    if (r < R && c < C) t[ty + i * 8][tx] = src[(size_t)r * C + c];
  }
  __syncthreads();
#pragma unroll
  for (int i = 0; i < 4; i++) {
    int c = ct0 + ty + i * 8, r = rt0 + tx;
    if (r < R && c < C) dst[(size_t)c * R + r] = f2bf(t[tx][ty + i * 8]);
  }
}

// ---------------- build X0 [T*B, 1024] bf16 : [emb(tok) | cnn] ----------------
__global__ void build_x0(const int* __restrict__ tok, const float* __restrict__ emb,
                         const float* __restrict__ cnn, short* __restrict__ X0) {
  int row = blockIdx.x;           // t*128 + b
  int t = row >> 7, b = row & 127;
  int tk = tok[b * T_ + t];
  const float* er = emb + (size_t)tk * 512;
  short* dst = X0 + (size_t)row * 1024;
  for (int i = threadIdx.x; i < 1024; i += 256)
    dst[i] = f2bf(i < 512 ? er[i] : cnn[b * 512 + (i - 512)]);
}

// ---------------- init: H[0] = [h0(-1) | h1(-1)] in FL layout; h0b[0], h1b[0] ----------------
__global__ void init_h(const float* __restrict__ ihs, float* h0f0, float* h1f0, short* H0) {
  int i = blockIdx.x * 256 + threadIdx.x;  // i = b*512 + h
  if (i < 65536) {
    int b = i >> 9, h = i & 511;
    float v0 = ihs[i], v1 = ihs[65536 + i];
    h0f0[i] = v0; h1f0[i] = v1;
    H0[FL(b, h)] = f2bf(v0);
    H0[FL(b, 512 + h)] = f2bf(v1);
  }
}

// ---------------- big MFMA GEMM core (A0 precompute + logits tiles) ----------------
struct GP {
  const short* A; const short* Bt;
  int lda, ldb, N, K;
  const float* bias0; const float* bias1; const float* bias2;
  float* fdst;
  float* outp; const float* bout;
};

template<int BM, int BN, int VAR>
__device__ __forceinline__ void gemm_core(const GP& p, short* la, short* lb, int bm, int bn, short* smem) {
  const int tid = threadIdx.x;
  const int wave = tid >> 6, lane = tid & 63;
  const int wm = wave >> 1, wn = wave & 1;
  constexpr int WM = BM / 2, WN = BN / 2;
  constexpr int MF = WM / 16, NF = WN / 16;
  const int lr = lane & 15, lg = lane >> 4;
  const short* Abase = p.A + (size_t)bm * BM * p.lda;
  const short* Bbase = p.Bt + (size_t)bn * BN * p.ldb;
  const int bnmax = p.N - bn * BN;
  f32x4 acc[MF][NF] = {};
  const int nkb = p.K >> 6;

  auto stA = [&](int buf, int k0) {
    constexpr int NI = BM / 32;
#pragma unroll
    for (int j = 0; j < NI; j++) {
      int glin = j * 256 + tid;
      int row = glin >> 3, gc = glin & 7;
      int gcs = gc ^ (row & 7);
      gload_lds16(Abase + (size_t)row * p.lda + k0 + gcs * 8,
                  &la[buf * BM * 64 + j * 2048 + wave * 512]);
    }
  };
  auto stB = [&](int buf, int k0) {
    constexpr int NI = BN / 32;
#pragma unroll
    for (int j = 0; j < NI; j++) {
      int glin = j * 256 + tid;
      int row = glin >> 3, gc = glin & 7;
      int gcs = gc ^ (row & 7);
      int rc = row < bnmax ? row : bnmax - 1;
      gload_lds16(Bbase + (size_t)rc * p.ldb + k0 + gcs * 8,
                  &lb[buf * BN * 64 + j * 2048 + wave * 512]);
    }
  };

  stA(0, 0); stB(0, 0);
  __syncthreads();
  int buf = 0;
  for (int kb = 0; kb < nkb; kb++) {
    if (kb + 1 < nkb) { stA(buf ^ 1, (kb + 1) * 64); stB(buf ^ 1, (kb + 1) * 64); }
    bf16x8 af[2][MF], bfr[2][NF];
#pragma unroll
    for (int ks = 0; ks < 2; ks++) {
#pragma unroll
      for (int m = 0; m < MF; m++) {
        int ar = wm * WM + m * 16 + lr;
        af[ks][m] = *(const bf16x8*)&la[buf * BM * 64 + (ar * 8 + ((ks * 4 + lg) ^ (ar & 7))) * 8];
      }
#pragma unroll
      for (int n = 0; n < NF; n++) {
        int br = wn * WN + n * 16 + lr;
        bfr[ks][n] = *(const bf16x8*)&lb[buf * BN * 64 + (br * 8 + ((ks * 4 + lg) ^ (br & 7))) * 8];
      }
    }
#pragma unroll
    for (int ks = 0; ks < 2; ks++)
#pragma unroll
      for (int m = 0; m < MF; m++)
#pragma unroll
        for (int n = 0; n < NF; n++)
          acc[m][n] = __builtin_amdgcn_mfma_f32_16x16x32_bf16(af[ks][m], bfr[ks][n], acc[m][n], 0, 0, 0);
    __syncthreads();
    buf ^= 1;
  }

  if constexpr (VAR == 0) {            // A0 = x@Wx + bias (3 gates), f32 row-major out
#pragma unroll
    for (int m = 0; m < MF; m++)
#pragma unroll
      for (int n = 0; n < NF; n++)
#pragma unroll
        for (int i = 0; i < 4; i++) {
          int row = bm * BM + wm * WM + m * 16 + lg * 4 + i;
          int col = bn * BN + wn * WN + n * 16 + lr;
          if (col >= p.N) continue;
          float bias = col < 512 ? p.bias0[col] : (col < 1024 ? p.bias1[col - 512] : p.bias2[col - 1024]);
          p.fdst[(size_t)row * 1536 + col] = acc[m][n][i] + bias;
        }
  } else {                             // VAR 5: logits -> smem transpose -> float4 full-line stores
    float* fs = (float*)smem;          // 128x128 f32 = 64 KiB
#pragma unroll
    for (int m = 0; m < MF; m++)
#pragma unroll
      for (int n = 0; n < NF; n++)
#pragma unroll
        for (int i = 0; i < 4; i++) {
          int lrow = wm * WM + m * 16 + lg * 4 + i;
          int lcol = wn * WN + n * 16 + lr;
          int col = bn * BN + lcol;
          fs[lrow * 128 + lcol] = acc[m][n][i] + (col < p.N ? p.bout[col] : 0.f);
        }
    __syncthreads();
#pragma unroll
    for (int j = 0; j < 16; j++) {
      int idx = j * 256 + tid;         // 0..4095 float4 slots
      int r = idx >> 5, c4 = (idx & 31) << 2;
      int gr = bm * BM + r;
      int tt = gr >> 7, b = gr & 127;
      int col = bn * BN + c4;
      if (col < p.N) {
        f32x4 v = *(const f32x4*)&fs[r * 128 + c4];
        *(f32x4*)&p.outp[((size_t)b * T_ + tt) * V_ + col] = v;
      }
    }
    __syncthreads();                   // smem reused across tiles by R_LOG
  }
}

template<int BM, int BN, int VAR>
__global__ __launch_bounds__(256) void gemm_one(GP p) {
  __shared__ short smem[2 * BM * 64 + 2 * BN * 64];
  gemm_core<BM, BN, VAR>(p, smem, smem + 2 * BM * 64, blockIdx.y, blockIdx.x, smem);
}

// ---------------- persistent recurrence kernel (step-rotated buffers + fused logits) ----------------
struct RP {
  short *Hb, *XCb, *RHb, *H1all;   // H: 26 x 131072 shorts; XC: 25 x 131072; RH: 25 x 65536
  float *u0b, *u1b, *h0b, *h1b;    // u: 25 x 65536 f32; h: 26 x 65536 f32
  const float *A0;
  const short *Whur0T, *Whc0T, *W1urT, *Wc1T;
  const float *bu1, *br1, *bc1;
  const short *WoutT; const float *bout;
  float *outp;
  int *bar;
};

template<int NKS>
__device__ __forceinline__ void wload(const short* __restrict__ Wt, int n0, int lane, bf16x8* wfr) {
  const short* p = Wt + (size_t)(n0 + (lane & 15)) * (NKS * 32) + ((lane >> 4) * 8);
#pragma unroll
  for (int ks = 0; ks < NKS; ks++) wfr[ks] = *(const bf16x8*)(p + (size_t)ks * 32);
}

// A-read via cached loads, 3-deep counted-vmcnt pipeline (chunk = 4 k-slices = 8 loads).
// SPLIT: slices [0,NKS/2) from Alo, [NKS/2,NKS) from Ahi (P3's A spans H[s+1].lo | H[s].hi).
template<int NKS, bool SPLIT>
__device__ __forceinline__ void kcompute(const short* __restrict__ Alo, const short* __restrict__ Ahi,
                                         int rb0, int lane, const bf16x8* __restrict__ wfr, f32x4* acc) {
  const short* aplo = Alo + rb0 * 512 + lane * 8;
  const short* aphi = Ahi + rb0 * 512 + lane * 8;
  constexpr int NCH = NKS / 4;
  constexpr int DEPTH = NCH < 3 ? NCH : 3;
  bf16x8 s0[4][4], s1[4][4];
#pragma unroll
  for (int c = 0; c < DEPTH; c++)
#pragma unroll
    for (int j = 0; j < 4; j++) {
      int ks = c * 4 + j;
      const short* ap = (SPLIT && ks >= NKS / 2) ? aphi : aplo;
      ncload16(&s0[c & 3][j], ap + ks * 4096);
      ncload16(&s1[c & 3][j], ap + ks * 4096 + 512);
    }
#pragma unroll
  for (int c = 0; c < NCH; c++) {
    const int issued = (DEPTH + c < NCH) ? DEPTH + c : NCH;
    vwait_n((issued - c - 1) * 8);
    __builtin_amdgcn_sched_barrier(0);
#pragma unroll
    for (int j = 0; j < 4; j++) {
      int ks = c * 4 + j;
      acc[ks & 1]       = __builtin_amdgcn_mfma_f32_16x16x32_bf16(s0[c & 3][j], wfr[ks], acc[ks & 1], 0, 0, 0);
      acc[2 + (ks & 1)] = __builtin_amdgcn_mfma_f32_16x16x32_bf16(s1[c & 3][j], wfr[ks], acc[2 + (ks & 1)], 0, 0, 0);
    }
    if (DEPTH + c < NCH) {
      const int nc = DEPTH + c;
#pragma unroll
      for (int j = 0; j < 4; j++) {
        int ks = nc * 4 + j;
        const short* ap = (SPLIT && ks >= NKS / 2) ? aphi : aplo;
        ncload16(&s0[nc & 3][j], ap + ks * 4096);
        ncload16(&s1[nc & 3][j], ap + ks * 4096 + 512);
      }
    }
  }
}

// Data-only hazards (rotation removed all WARs); per-WG flags = completed steps:
//  P3(s): all P2 flags >= s+1 [H[s+1].lo], all P4 flags >= s [H[s].hi, h1b[s], s>=1]
//  P1(s): all P2 flags >= s   [H[s].lo, h0b[s], s>=1]
//  P4(s): all P3 flags >= s+1 [xc[s].hi, u1b[s]], all P2 flags >= s+1 [xc[s].lo]
//  P2(s): all P1 flags >= s+1 [u0b[s], rh0b[s]]
//  R_LOG tile(t,bn): all P4 flags >= t+1 [H1all[t]]
__global__ __launch_bounds__(256, 1) void recurrence(RP p) {
  __shared__ short smem[2 * 128 * 64 + 2 * 128 * 64];   // used by R_LOG only (64 KiB)
  const int bid = blockIdx.x;
  int* bar = p.bar;
  const int tid = threadIdx.x, wv = tid >> 6, lane = tid & 63;
  const int lr = lane & 15, lg = lane >> 4;

  if (bid >= 192) {
    // ---- R_LOG: logits tiles, gated on P4 step flags ----
    const int w = bid - 192;
    GP g = {};
    g.A = p.H1all; g.lda = 512; g.Bt = p.WoutT; g.ldb = 512; g.N = V_; g.K = 512;
    g.outp = p.outp; g.bout = p.bout;
    int done_t = 0;
    for (int idx = w; idx < 79 * 25; idx += 64) {
      int t = idx / 79, bn = idx % 79;
      if (t + 1 > done_t) { waitflag(bar, R_P4, 32, t + 1); done_t = t + 1; }
      gemm_core<128, 128, 5>(g, smem, smem + 2 * 128 * 64, t, bn, smem);
    }
    return;
  }

  const int m8 = bid & 7;
  const int k = ((bid & 127) >> 3) * 4 + (m8 & 3);   // role-pinned: P3/P4 on XCD 0-3, P1/P2 on 4-7
  const int role = (bid < 128) ? ((m8 < 4) ? R_P3 : R_P1) : ((m8 < 4) ? R_P4 : R_P2);
  const int nt = k >> 1, mh = k & 1;
  const int colb = nt * 32 + (wv & 1) * 16;
  const int rb0 = mh * 4 + (wv >> 1) * 2;
  const int col = colb + lr;

  if (role == R_P3) {
    // ---- layer-1 u,r gates: out[128,1024], K=1024, A = H[s+1].lo | H[s].hi ----
    bf16x8 wfr[32]; wload<32>(p.W1urT, colb, lane, wfr);
    for (int s = 0; s < T_; s++) {
      if (s >= 1) waitflag2(bar, R_P2, 32, s + 1, R_P4, 32, s);
      else        waitflag(bar, R_P2, 32, 1);
      const short* Hs1 = p.Hb + (size_t)(s + 1) * 131072;
      const short* Hs  = p.Hb + (size_t)s * 131072;
      f32x4 acc[4] = {};
      kcompute<32, true>(Hs1, Hs, rb0, lane, wfr, acc);
      f32x4 am[2] = { acc[0] + acc[1], acc[2] + acc[3] };
      short* xc = p.XCb + (size_t)s * 131072;
      const float* h1s = p.h1b + (size_t)s * 65536;
      float* u1s = p.u1b + (size_t)s * 65536;
#pragma unroll
      for (int m = 0; m < 2; m++)
#pragma unroll
        for (int i = 0; i < 4; i++) {
          int row = (rb0 + m) * 16 + lg * 4 + i;
          if (colb < 512) {
            cstoref(&u1s[row * 512 + col], sigm(am[m][i] + p.bu1[col]));
          } else {
            float sg = sigm(am[m][i] + p.br1[col - 512]);
            cstores(&xc[FL(row, col)], f2bf(sg * h1s[row * 512 + (col - 512)]));
          }
        }
      setflag(bar, R_P3, k, s + 1);
    }
  } else if (role == R_P1) {
    // ---- layer-0 u,r gates: out[128,1024], K=512, A = H[s].lo ----
    bf16x8 wfr[16]; wload<16>(p.Whur0T, colb, lane, wfr);
    for (int s = 0; s < T_; s++) {
      if (s >= 1) waitflag(bar, R_P2, 32, s);
      const short* Hs = p.Hb + (size_t)s * 131072;
      f32x4 acc[4] = {};
      kcompute<16, false>(Hs, Hs, rb0, lane, wfr, acc);
      f32x4 am[2] = { acc[0] + acc[1], acc[2] + acc[3] };
      const float* a0s = p.A0 + (size_t)s * 196608;
      const float* h0s = p.h0b + (size_t)s * 65536;
      float* u0s = p.u0b + (size_t)s * 65536;
      short* rh = p.RHb + (size_t)s * 65536;
#pragma unroll
      for (int m = 0; m < 2; m++)
#pragma unroll
        for (int i = 0; i < 4; i++) {
          int row = (rb0 + m) * 16 + lg * 4 + i;
          if (colb < 512) {
            cstoref(&u0s[row * 512 + col], sigm(am[m][i] + a0s[row * 1536 + col]));
          } else {
            float sg = sigm(am[m][i] + a0s[row * 1536 + col]);
            cstores(&rh[FL(row, col - 512)], f2bf(sg * h0s[row * 512 + (col - 512)]));
          }
        }
      setflag(bar, R_P1, k, s + 1);
    }
  } else if (role == R_P4) {
    // ---- layer-1 cand + h1 update: out[128,512], K=1024, A = xc[s] ----
    bf16x8 wfr[32]; wload<32>(p.Wc1T, colb, lane, wfr);
    for (int s = 0; s < T_; s++) {
      waitflag2(bar, R_P3, 64, s + 1, R_P2, 32, s + 1);
      const short* xc = p.XCb + (size_t)s * 131072;
      f32x4 acc[4] = {};
      kcompute<32, false>(xc, xc, rb0, lane, wfr, acc);
      f32x4 am[2] = { acc[0] + acc[1], acc[2] + acc[3] };
      const float* u1s = p.u1b + (size_t)s * 65536;
      const float* h1s = p.h1b + (size_t)s * 65536;
      float* h1d = p.h1b + (size_t)(s + 1) * 65536;
      short* xh = p.Hb + (size_t)(s + 1) * 131072;
#pragma unroll
      for (int m = 0; m < 2; m++)
#pragma unroll
        for (int i = 0; i < 4; i++) {
          int row = (rb0 + m) * 16 + lg * 4 + i;
          float cc = tanhfast(am[m][i] + p.bc1[col]);
          float u = u1s[row * 512 + col], h = h1s[row * 512 + col];
          float hn = u * h + (1.f - u) * cc;
          cstoref(&h1d[row * 512 + col], hn);
          short hb = f2bf(hn);
          cstores(&xh[FL(row, 512 + col)], hb);
          cstores(&p.H1all[(size_t)s * 65536 + row * 512 + col], hb);  // read by R_LOG (IC-coherent)
          if (s == T_ - 1) p.outp[32000000 + 65536 + row * 512 + col] = hn;
        }
      setflag(bar, R_P4, k, s + 1);
    }
  } else {
    // ---- layer-0 cand + h0 update: out[128,512], K=512, A = rh0b[s] ----
    bf16x8 wfr[16]; wload<16>(p.Whc0T, colb, lane, wfr);
    for (int s = 0; s < T_; s++) {
      waitflag(bar, R_P1, 64, s + 1);
      const short* rh = p.RHb + (size_t)s * 65536;
      f32x4 acc[4] = {};
      kcompute<16, false>(rh, rh, rb0, lane, wfr, acc);
      f32x4 am[2] = { acc[0] + acc[1], acc[2] + acc[3] };
      const float* a0s = p.A0 + (size_t)s * 196608;
      const float* u0s = p.u0b + (size_t)s * 65536;
      const float* h0s = p.h0b + (size_t)s * 65536;
      float* h0d = p.h0b + (size_t)(s + 1) * 65536;
      short* xh  = p.Hb + (size_t)(s + 1) * 131072;
      short* xcw = p.XCb + (size_t)s * 131072;
#pragma unroll
      for (int m = 0; m < 2; m++)
#pragma unroll
        for (int i = 0; i < 4; i++) {
          int row = (rb0 + m) * 16 + lg * 4 + i;
          float c = tanhfast(am[m][i] + a0s[row * 1536 + 1024 + col]);
          float u = u0s[row * 512 + col], h = h0s[row * 512 + col];
          float hn = u * h + (1.f - u) * c;
          cstoref(&h0d[row * 512 + col], hn);
          short hb = f2bf(hn);
          cstores(&xh[FL(row, col)], hb);
          cstores(&xcw[FL(row, col)], hb);
          if (s == T_ - 1) p.outp[32000000 + row * 512 + col] = hn;
        }
      setflag(bar, R_P2, k, s + 1);
    }
  }
}

// ---------------- host ----------------
extern "C" void kernel_launch(void* const* d_in, const int* in_sizes, int n_in,
                              void* d_out, int out_size, void* d_ws, size_t ws_size,
                              hipStream_t stream) {
  const int*   tokens = (const int*)  d_in[0];
  const float* cnn    = (const float*)d_in[1];
  const float* ihs    = (const float*)d_in[2];
  const float* emb    = (const float*)d_in[3];
  const float* Wu0 = (const float*)d_in[4];
  const float* Wr0 = (const float*)d_in[5];
  const float* Wc0 = (const float*)d_in[6];
  const float* bu0 = (const float*)d_in[7];
  const float* br0 = (const float*)d_in[8];
  const float* bc0 = (const float*)d_in[9];
  const float* Wu1 = (const float*)d_in[10];
  const float* Wr1 = (const float*)d_in[11];
  const float* Wc1 = (const float*)d_in[12];
  const float* bu1 = (const float*)d_in[13];
  const float* br1 = (const float*)d_in[14];
  const float* bc1 = (const float*)d_in[15];
  const float* Wout = (const float*)d_in[16];
  const float* bout = (const float*)d_in[17];
  float* out = (float*)d_out;

  char* w = (char*)d_ws;
  size_t off = 0;
  auto alloc = [&](size_t bytes) { void* p = w + off; off += (bytes + 255) & ~255ull; return p; };
  short* WxT    = (short*)alloc(1536 * 1024 * 2);
  short* Whur0T = (short*)alloc(1024 * 512 * 2);
  short* Whc0T  = (short*)alloc(512 * 512 * 2);
  short* W1urT  = (short*)alloc(1024 * 1024 * 2);
  short* Wc1T   = (short*)alloc(512 * 1024 * 2);
  short* WoutT  = (short*)alloc((size_t)10000 * 512 * 2);
  short* X0     = (short*)alloc((size_t)3200 * 1024 * 2);
  float* A0     = (float*)alloc((size_t)3200 * 1536 * 4);
  short* H1all  = (short*)alloc((size_t)3200 * 512 * 2);
  // step-rotated state (fresh addresses per step -> cached reads are coherence-safe)
  short* Hb     = (short*)alloc((size_t)26 * 131072 * 2);
  short* XCb    = (short*)alloc((size_t)25 * 131072 * 2);
  short* RHb    = (short*)alloc((size_t)25 * 65536 * 2);
  float* u0b    = (float*)alloc((size_t)25 * 65536 * 4);
  float* u1b    = (float*)alloc((size_t)25 * 65536 * 4);
  float* h0b    = (float*)alloc((size_t)26 * 65536 * 4);
  float* h1b    = (float*)alloc((size_t)26 * 65536 * 4);
  int*   bar    = (int*)alloc(4096);
  (void)ws_size; (void)in_sizes; (void)n_in; (void)out_size;

  {
    TJobs J;
    J.j[0] = { Wu0,              WxT,                1024, 512,  0    };
    J.j[1] = { Wr0,              WxT + 512 * 1024,   1024, 512,  512  };
    J.j[2] = { Wc0,              WxT + 1024 * 1024,  1024, 512,  1024 };
    J.j[3] = { Wu0 + 1024 * 512, Whur0T,             512,  512,  1536 };
    J.j[4] = { Wr0 + 1024 * 512, Whur0T + 512 * 512, 512,  512,  1792 };
    J.j[5] = { Wc0 + 1024 * 512, Whc0T,              512,  512,  2048 };
    J.j[6] = { Wu1,              W1urT,              1024, 512,  2304 };
    J.j[7] = { Wr1,              W1urT + 512 * 1024, 1024, 512,  2816 };
    J.j[8] = { Wc1,              Wc1T,               1024, 512,  3328 };
    J.j[9] = { Wout,             WoutT,              512,  10000, 3840 };
    tcast_all<<<8848, dim3(32, 8), 0, stream>>>(J);
  }

  build_x0<<<3200, 256, 0, stream>>>(tokens, emb, cnn, X0);
  init_h<<<256, 256, 0, stream>>>(ihs, h0b, h1b, Hb);
  hipMemsetAsync(bar, 0, 4096, stream);   // flags are monotone per dispatch: re-zero every call

  // A0 = X0 @ WxT^T + biases : [3200,1536] f32
  {
    GP g = {};
    g.A = X0; g.lda = 1024; g.Bt = WxT; g.ldb = 1024; g.N = 1536; g.K = 1024;
    g.bias0 = bu0; g.bias1 = br0; g.bias2 = bc0; g.fdst = A0;
    gemm_one<128, 128, 0><<<dim3(12, 25), 256, 0, stream>>>(g);
  }

  // persistent recurrence + fused logits: 192 role WGs + 64 logits WGs
  {
    RP r = {};
    r.Hb = Hb; r.XCb = XCb; r.RHb = RHb; r.H1all = H1all;
    r.u0b = u0b; r.u1b = u1b; r.h0b = h0b; r.h1b = h1b;
    r.A0 = A0;
    r.Whur0T = Whur0T; r.Whc0T = Whc0T; r.W1urT = W1urT; r.Wc1T = Wc1T;
    r.bu1 = bu1; r.br1 = br1; r.bc1 = bc1;
    r.WoutT = WoutT; r.bout = bout;
    r.outp = out;
    r.bar = bar;
    recurrence<<<dim3(NWG_), 256, 0, stream>>>(r);
  }
}